// Round 1
// baseline (3144.068 us; speedup 1.0000x reference)
//
#include <hip/hip_runtime.h>
#include <cstddef>
#include <cstdint>

// ---------------------------------------------------------------------------
// BatchGRU round 5: cut the recurrent kernel's L2 weight re-stream in half.
// gru3_k re-read 583 KB of packed W_hh per block per step from L2 (19 GB per
// dispatch, ~26 B/cyc/CU effective) -> streaming-bound at 9.96 us/step.
// gru4_k makes weights resident: kt 0..2 persistent in VGPRs (72/wave),
// kt 3..4 in LDS (114 KB), kt 5..9 streamed. Streamed bytes/step: 291 KB.
// Plus: device-side counting sort of segments by length (descending) so
// forward blocks early-exit at the group max length (backward needs all 128
// steps: padding prefix legitimately evolves h). perm/gmax live in the PkI
// region, which is dead after xp_gemm_k -> FAST_NEED unchanged.
// ---------------------------------------------------------------------------

typedef short s8v __attribute__((ext_vector_type(8)));   // 8 x bf16 (bits)
typedef float f4v __attribute__((ext_vector_type(4)));   // MFMA accum

#define NSEG   2048
#define HID    300
#define HPAD   320
#define MAXLEN 128
#define NTOT   131072
#define PKSTRIDE 307200   // shorts per dir in PkH / PkI

__device__ __forceinline__ short f2bf(float f){
  unsigned u = __float_as_uint(f);
  u = (u + 0x7FFFu + ((u >> 16) & 1u)) >> 16;   // RNE
  return (short)u;
}
__device__ __forceinline__ float bf2f(unsigned short u){
  return __uint_as_float((unsigned)u << 16);
}
__device__ __forceinline__ float sigm(float x){ return 1.f / (1.f + __expf(-x)); }
__device__ __forceinline__ float tanha(float x){ return 1.f - 2.f / (__expf(2.f * x) + 1.f); }

// ---------------------------------------------------------------------------
// starts[b] = exclusive prefix sum of a_scope
// ---------------------------------------------------------------------------
__global__ __launch_bounds__(1024)
void scan_starts_k(const int* __restrict__ a_scope, int* __restrict__ starts){
  __shared__ int buf[2][NSEG];
  const int tid = threadIdx.x;
  for (int i = tid; i < NSEG; i += 1024) buf[0][i] = a_scope[i];
  __syncthreads();
  int src = 0;
  for (int off = 1; off < NSEG; off <<= 1){
    for (int i = tid; i < NSEG; i += 1024){
      int v = buf[src][i];
      if (i >= off) v += buf[src][i - off];
      buf[1 - src][i] = v;
    }
    __syncthreads();
    src ^= 1;
  }
  for (int i = tid; i < NSEG; i += 1024) starts[i] = buf[src][i] - a_scope[i];
}

// ---------------------------------------------------------------------------
// h0[b][k] = max over t<len of raw node[starts[b]+t][k]  (k>=HID -> 0 pad)
// ---------------------------------------------------------------------------
__global__ void h0_max_k(const float* __restrict__ node, const int* __restrict__ a_scope,
                         const int* __restrict__ starts, float* __restrict__ h0){
  const int b = blockIdx.x;
  const int k = threadIdx.x;              // 320 threads
  const int s = starts[b], len = a_scope[b];
  float m = 0.f;
  if (k < HID){
    m = -3.402823466e38f;
    const float* p = node + (size_t)s * HID + k;
    for (int t = 0; t < len; ++t) m = fmaxf(m, p[(size_t)t * HID]);
  }
  h0[(size_t)b * HPAD + k] = m;
}

// ---------------------------------------------------------------------------
// Counting sort of segments by length, DESCENDING (bin = 128 - len).
// perm[p] = original segment id; gmax[g] = max length in group g (= first
// element of the group, since the sequence is non-increasing).
// Order within equal-length bins is arbitrary (atomics) - values unaffected.
// ---------------------------------------------------------------------------
__global__ __launch_bounds__(256)
void sort_segs_k(const int* __restrict__ a_scope, int* __restrict__ perm,
                 int* __restrict__ gmax){
  __shared__ int cnt[MAXLEN + 1];
  __shared__ int sp[NSEG];
  const int tid = threadIdx.x;
  for (int i = tid; i < MAXLEN + 1; i += 256) cnt[i] = 0;
  __syncthreads();
  for (int i = tid; i < NSEG; i += 256) atomicAdd(&cnt[MAXLEN - a_scope[i]], 1);
  __syncthreads();
  if (tid == 0){
    int s = 0;
    for (int b = 0; b <= MAXLEN; ++b){ int c = cnt[b]; cnt[b] = s; s += c; }
  }
  __syncthreads();
  for (int i = tid; i < NSEG; i += 256){
    int p = atomicAdd(&cnt[MAXLEN - a_scope[i]], 1);
    sp[p] = i;
  }
  __syncthreads();
  for (int i = tid; i < NSEG; i += 256) perm[i] = sp[i];
  for (int g = tid; g < NSEG / 16; g += 256) gmax[g] = a_scope[sp[g * 16]];
}

// ===========================================================================
// FAST PATH
// ===========================================================================
// prep2: pack W_hh (PkH) and W_ih (PkI) into MFMA B-fragment order, bf16.
// Layout: [dir][sec 0..2 (r,z,n)][jt 0..19][kt 0..9][lane 0..63][e 0..7]
// B lane map: j = jt*16 + (lane&15); k = kt*32 + (lane>>4)*8 + e; K padded 320.
// gbias: [dir][4][320]  (r: bih+bhh, z: bih+bhh, xn: bih, hn: bhh)
// ---------------------------------------------------------------------------
__global__ void prep2_k(const float* __restrict__ wih_f, const float* __restrict__ whh_f,
                        const float* __restrict__ bih_f, const float* __restrict__ bhh_f,
                        const float* __restrict__ wih_b, const float* __restrict__ whh_b,
                        const float* __restrict__ bih_b, const float* __restrict__ bhh_b,
                        short* __restrict__ PkH, short* __restrict__ PkI,
                        float* __restrict__ gbias){
  const int idx = blockIdx.x * 256 + threadIdx.x;
  if (idx < 1228800){
    const bool isH = idx < 614400;
    int t = isH ? idx : idx - 614400;
    int e = t & 7, lane = (t >> 3) & 63;
    int r = t >> 9;
    int kt = r % 10; r /= 10;
    int jt = r % 20; r /= 20;
    int sec = r % 3, d = r / 3;          // per-dir stride = PKSTRIDE shorts
    const float* w = isH ? (d ? whh_b : whh_f) : (d ? wih_b : wih_f);
    int j = jt * 16 + (lane & 15);
    int k = kt * 32 + (lane >> 4) * 8 + e;
    float v = 0.f;
    if (j < HID && k < HID) v = w[(sec * HID + j) * HID + k];
    (isH ? PkH : PkI)[t] = f2bf(v);
  } else if (idx < 1228800 + 2560){
    int r3 = idx - 1228800;
    int d = r3 / 1280;
    int rem = r3 - d * 1280;
    int sec = rem / HPAD;
    int j = rem - sec * HPAD;
    const float* bih = d ? bih_b : bih_f;
    const float* bhh = d ? bhh_b : bhh_f;
    float v = 0.f;
    if (j < HID){
      if (sec == 0)      v = bih[j] + bhh[j];
      else if (sec == 1) v = bih[HID + j] + bhh[HID + j];
      else if (sec == 2) v = bih[2 * HID + j];
      else               v = bhh[2 * HID + j];
    }
    gbias[r3] = v;
  }
}

// ---------------------------------------------------------------------------
// xp GEMM: xp[dir][row][g] = (relu(node[row]+bias) @ W_ih_dir^T)[g], bf16.
// ---------------------------------------------------------------------------
__global__ __launch_bounds__(256)
void xp_gemm_k(const float* __restrict__ node, const float* __restrict__ bias,
               const short* __restrict__ PkI, short* __restrict__ xp){
  __shared__ __align__(16) short Bt[4 * 5120];   // 40 KB: 4 tiles x [10 kt][512]
  const int dir = blockIdx.x & 1;
  const int blk = blockIdx.x >> 1;               // 0..1023
  const int tid = threadIdx.x;
  const int wave = tid >> 6, lane = tid & 63;
  const int quad = lane >> 4, lc = lane & 15, l8 = lane << 3;
  const int rowbase = blk * 128 + wave * 32;
  const short* PI = PkI + (size_t)dir * PKSTRIDE;
  short* xpd = xp + (size_t)dir * ((size_t)NTOT * 900);

  // A fragments in registers: 2 tiles x 10 kt (rows read once, fp32->relu->bf16)
  s8v A[2][10];
  #pragma unroll
  for (int tm = 0; tm < 2; ++tm){
    const float* src = node + (size_t)(rowbase + tm * 16 + lc) * HID;
    #pragma unroll
    for (int kt = 0; kt < 10; ++kt){
      const int k0 = kt * 32 + quad * 8;
      s8v a;
      #pragma unroll
      for (int e = 0; e < 8; ++e){
        const int k = k0 + e;
        float v = 0.f;
        if (k < HID){ v = src[k] + bias[k]; v = v > 0.f ? v : 0.f; }
        a[e] = f2bf(v);
      }
      A[tm][kt] = a;
    }
  }

  for (int st0 = 0; st0 < 60; st0 += 4){
    __syncthreads();
    for (int i = tid; i < 2560; i += 256)
      ((s8v*)Bt)[i] = ((const s8v*)(PI + (size_t)st0 * 5120))[i];
    __syncthreads();
    #pragma unroll
    for (int u = 0; u < 4; ++u){
      const int st = st0 + u;                 // st = sec*20 + jt
      const int sec = st / 20, jt = st % 20;
      f4v a0 = {0.f,0.f,0.f,0.f}, a1 = {0.f,0.f,0.f,0.f};
      #pragma unroll
      for (int kt = 0; kt < 10; ++kt){
        const s8v b = *(const s8v*)&Bt[u * 5120 + kt * 512 + l8];
        a0 = __builtin_amdgcn_mfma_f32_16x16x32_bf16(A[0][kt], b, a0, 0, 0, 0);
        a1 = __builtin_amdgcn_mfma_f32_16x16x32_bf16(A[1][kt], b, a1, 0, 0, 0);
      }
      const int j = jt * 16 + lc;
      if (j < HID){
        const int g = sec * HID + j;
        #pragma unroll
        for (int r = 0; r < 4; ++r){
          const int rr = rowbase + quad * 4 + r;
          xpd[(size_t)rr * 900 + g]        = f2bf(a0[r]);
          xpd[(size_t)(rr + 16) * 900 + g] = f2bf(a1[r]);
        }
      }
    }
  }
}

// ---------------------------------------------------------------------------
// Recurrent kernel round 5 (gru4_k): 256 blocks (128 sorted seg-groups x 2
// dirs), 640 threads / 10 waves. Wave w owns jt {2w, 2w+1} (wave 9: jt 18).
// Weight residency per wave: kt 0..2 in VGPRs (18 frags, 72 regs), kt 3..4 in
// LDS (12 tiles, shared LDS block 114 KB), kt 5..9 streamed from L2 per step.
// Accumulation order over kt unchanged (0..9) -> bit-identical vs gru3_k.
// Forward blocks run only gmax[g] steps (outputs beyond group max are never
// written, h is discarded); backward runs all 128 (padding prefix evolves h).
// ---------------------------------------------------------------------------
__global__ __launch_bounds__(640, 3)
void gru4_k(const int* __restrict__ a_scope, const int* __restrict__ starts,
            const int* __restrict__ perm, const int* __restrict__ gmax,
            const float* __restrict__ h0, const short* __restrict__ PkH,
            const float* __restrict__ gbias, const short* __restrict__ xp,
            float* __restrict__ out){
  __shared__ __align__(16) short WL[114 * 512];   // 116,736 B: kt 3..4 weights
  __shared__ __align__(16) short hbuf[16][328];   // 10,496 B: bf16 h (A operand)

  const int dir  = blockIdx.x & 1;
  const int g    = blockIdx.x >> 1;
  const int seg0 = g * 16;
  const int tid  = threadIdx.x;
  const int wave = tid >> 6;
  const int lane = tid & 63;
  const int quad = lane >> 4;
  const int lc   = lane & 15;
  const int l8   = lane << 3;
  const int jt0  = 2 * wave;
  const int njt  = (jt0 < 18) ? 2 : 1;   // wave 9 handles jt 18 only

  const short* PH = PkH + (size_t)dir * PKSTRIDE;

  // ---- persistent B fragments: kt 0..2 (72 VGPRs/wave) ----
  s8v Bp[2][3][3];
  #pragma unroll
  for (int i = 0; i < 2; ++i){
    #pragma unroll
    for (int s = 0; s < 3; ++s){
      #pragma unroll
      for (int kt = 0; kt < 3; ++kt){
        if (i < njt)
          Bp[i][s][kt] = *(const s8v*)(PH + (size_t)((s * 20 + jt0 + i) * 10 + kt) * 512 + l8);
      }
    }
  }

  // ---- LDS B fragments: kt 3..4; tile id = wave*12 + (i*3+s)*2 + ktl ----
  #pragma unroll
  for (int i = 0; i < 2; ++i){
    if (i < njt){
      #pragma unroll
      for (int s = 0; s < 3; ++s){
        #pragma unroll
        for (int ktl = 0; ktl < 2; ++ktl){
          *(s8v*)&WL[(size_t)(wave * 12 + (i * 3 + s) * 2 + ktl) * 512 + l8] =
            *(const s8v*)(PH + (size_t)((s * 20 + jt0 + i) * 10 + 3 + ktl) * 512 + l8);
        }
      }
    }
  }

  // per-thread segment rows (m = quad*4 + r), via sorted perm
  int ls_r[4], ll_r[4];
  #pragma unroll
  for (int r = 0; r < 4; ++r){
    const int sg = perm[seg0 + quad * 4 + r];
    ls_r[r] = starts[sg];
    ll_r[r] = a_scope[sg];
  }

  // init hbuf cooperatively (16 x 320 entries over 640 threads)
  for (int i = tid; i < 16 * HPAD; i += 640){
    const int m = i / HPAD, k = i - m * HPAD;
    hbuf[m][k] = f2bf(h0[(size_t)perm[seg0 + m] * HPAD + k]);
  }

  // per-thread h master + biases in registers (columns j = (jt0+i)*16 + lc)
  float hprev[2][4];
  float bR[2], bZ[2], bX[2], bH[2];
  bool  jv[2];
  #pragma unroll
  for (int i = 0; i < 2; ++i){
    const int jt = jt0 + i;
    const int j  = jt * 16 + lc;
    jv[i] = (jt < 19) && (j < HID);
    bR[i] = bZ[i] = bX[i] = bH[i] = 0.f;
    hprev[i][0] = hprev[i][1] = hprev[i][2] = hprev[i][3] = 0.f;
    if (jv[i]){
      bR[i] = gbias[dir * 1280 + 0 * HPAD + j];
      bZ[i] = gbias[dir * 1280 + 1 * HPAD + j];
      bX[i] = gbias[dir * 1280 + 2 * HPAD + j];
      bH[i] = gbias[dir * 1280 + 3 * HPAD + j];
      #pragma unroll
      for (int r = 0; r < 4; ++r)
        hprev[i][r] = h0[(size_t)perm[seg0 + quad * 4 + r] * HPAD + j];
    }
  }
  __syncthreads();

  const unsigned short* xpd = (const unsigned short*)xp + (size_t)dir * ((size_t)NTOT * 900);
  const int nsteps = dir ? MAXLEN : gmax[g];   // fwd: early-exit at group max

  for (int step = 0; step < nsteps; ++step){
    const int t = dir ? (MAXLEN - 1 - step) : step;

    // ---- xp gate preactivations (h-independent; overlap with MFMA stream) --
    float xg[2][4][3];
    #pragma unroll
    for (int i = 0; i < 2; ++i){
      const int j = (jt0 + i) * 16 + lc;
      #pragma unroll
      for (int r = 0; r < 4; ++r){
        float vr = 0.f, vz = 0.f, vn = 0.f;
        if (jv[i] && t < ll_r[r]){
          const unsigned short* p = xpd + (size_t)(ls_r[r] + t) * 900 + j;
          vr = bf2f(p[0]); vz = bf2f(p[300]); vn = bf2f(p[600]);
        }
        xg[i][r][0] = vr; xg[i][r][1] = vz; xg[i][r][2] = vn;
      }
    }

    __syncthreads();   // hbuf(t) complete (written end of previous step)

    // ---- h-GEMM: acc[i][sec], K=320 over 10 kt (regs -> LDS -> streamed) ----
    f4v acc[2][3];
    #pragma unroll
    for (int i = 0; i < 2; ++i)
      #pragma unroll
      for (int s = 0; s < 3; ++s)
        acc[i][s] = f4v{0.f, 0.f, 0.f, 0.f};

    // kt 0..2: persistent VGPR fragments
    #pragma unroll
    for (int kt = 0; kt < 3; ++kt){
      const s8v a = *(const s8v*)&hbuf[lc][kt * 32 + quad * 8];
      #pragma unroll
      for (int i = 0; i < 2; ++i){
        if (i < njt){
          #pragma unroll
          for (int s = 0; s < 3; ++s)
            acc[i][s] = __builtin_amdgcn_mfma_f32_16x16x32_bf16(a, Bp[i][s][kt], acc[i][s], 0, 0, 0);
        }
      }
    }
    // kt 3..4: LDS-resident fragments
    #pragma unroll
    for (int ktl = 0; ktl < 2; ++ktl){
      const s8v a = *(const s8v*)&hbuf[lc][(3 + ktl) * 32 + quad * 8];
      #pragma unroll
      for (int i = 0; i < 2; ++i){
        if (i < njt){
          #pragma unroll
          for (int s = 0; s < 3; ++s){
            const s8v b = *(const s8v*)&WL[(size_t)(wave * 12 + (i * 3 + s) * 2 + ktl) * 512 + l8];
            acc[i][s] = __builtin_amdgcn_mfma_f32_16x16x32_bf16(a, b, acc[i][s], 0, 0, 0);
          }
        }
      }
    }
    // kt 5..9: streamed from L2 (291 KB/block/step, was 583)
    #pragma unroll 2
    for (int kt = 5; kt < 10; ++kt){
      const s8v a = *(const s8v*)&hbuf[lc][kt * 32 + quad * 8];
      #pragma unroll
      for (int i = 0; i < 2; ++i){
        if (i < njt){
          #pragma unroll
          for (int s = 0; s < 3; ++s){
            const s8v b = *(const s8v*)(PH + (size_t)((s * 20 + jt0 + i) * 10 + kt) * 512 + l8);
            acc[i][s] = __builtin_amdgcn_mfma_f32_16x16x32_bf16(a, b, acc[i][s], 0, 0, 0);
          }
        }
      }
    }
    __syncthreads();   // all waves done reading hbuf before rewrite

    // ---- gates + h update + output (owning thread, registers only) ----
    #pragma unroll
    for (int i = 0; i < 2; ++i){
      if (jv[i]){
        const int j = (jt0 + i) * 16 + lc;
        #pragma unroll
        for (int r = 0; r < 4; ++r){
          const int m = quad * 4 + r;
          const float rg = sigm(acc[i][0][r] + bR[i] + xg[i][r][0]);
          const float zg = sigm(acc[i][1][r] + bZ[i] + xg[i][r][1]);
          const float ng = tanha(xg[i][r][2] + bX[i] + rg * (acc[i][2][r] + bH[i]));
          const float hnew = (1.f - zg) * ng + zg * hprev[i][r];
          hprev[i][r] = hnew;
          hbuf[m][j] = f2bf(hnew);
          if (t < ll_r[r])
            out[(size_t)(ls_r[r] + t) * 600 + dir * HID + j] = hnew;
        }
      }
    }
  }
}

// ===========================================================================
// FALLBACK PATH (round-1, known-passing) — used when ws_size is too small.
// ===========================================================================
__global__ void prep_k(const float* __restrict__ wih_f, const float* __restrict__ whh_f,
                       const float* __restrict__ bih_f, const float* __restrict__ bhh_f,
                       const float* __restrict__ wih_b, const float* __restrict__ whh_b,
                       const float* __restrict__ bih_b, const float* __restrict__ bhh_b,
                       short* __restrict__ PkA, short* __restrict__ PkB,
                       float* __restrict__ gbias){
  const int idx = blockIdx.x * 256 + threadIdx.x;
  if (idx < 819200){
    int e = idx & 7, lane = (idx >> 3) & 63;
    int r = idx >> 9;
    int kt = r % 20; r /= 20;
    int jt = r % 20; r /= 20;
    int sec = r & 1, d = r >> 1;
    const float* wih = d ? wih_b : wih_f;
    const float* whh = d ? whh_b : whh_f;
    int j = jt * 16 + (lane & 15);
    int k = kt * 32 + (lane >> 4) * 8 + e;
    float v = 0.f;
    if (j < HID){
      int row = sec * HID + j;
      if (k < HID)                    v = wih[row * HID + k];
      else if (k >= 320 && k < 620)   v = whh[row * HID + (k - 320)];
    }
    PkA[idx] = f2bf(v);
  } else if (idx < 819200 + 409600){
    int t = idx - 819200;
    int e = t & 7, lane = (t >> 3) & 63;
    int r = t >> 9;
    int kt = r % 10; r /= 10;
    int jt = r % 20; r /= 20;
    int sec = r & 1, d = r >> 1;
    const float* w = sec ? (d ? whh_b : whh_f) : (d ? wih_b : wih_f);
    int j = jt * 16 + (lane & 15);
    int k = kt * 32 + (lane >> 4) * 8 + e;
    float v = 0.f;
    if (j < HID && k < HID) v = w[(600 + j) * HID + k];
    PkB[t] = f2bf(v);
  } else if (idx < 819200 + 409600 + 2560){
    int r3 = idx - 819200 - 409600;
    int d = r3 / 1280;
    int rem = r3 - d * 1280;
    int sec = rem / HPAD;
    int j = rem - sec * HPAD;
    const float* bih = d ? bih_b : bih_f;
    const float* bhh = d ? bhh_b : bhh_f;
    float v = 0.f;
    if (j < HID){
      if (sec == 0)      v = bih[j] + bhh[j];
      else if (sec == 1) v = bih[HID + j] + bhh[HID + j];
      else if (sec == 2) v = bih[2 * HID + j];
      else               v = bhh[2 * HID + j];
    }
    gbias[r3] = v;
  }
}

__global__ __launch_bounds__(256)
void gru_k(const float* __restrict__ node, const float* __restrict__ bias,
           const int* __restrict__ a_scope, const int* __restrict__ starts,
           const float* __restrict__ h0, const short* __restrict__ PkA,
           const short* __restrict__ PkB, const float* __restrict__ gbias,
           float* __restrict__ out){
  __shared__ __align__(16) short xbuf[16][328];
  __shared__ __align__(16) short hbuf[16][328];
  __shared__ float hfp[16][324];
  __shared__ float lbias[4][HPAD];
  __shared__ int ls[16], ll[16];

  const int dir  = blockIdx.x & 1;
  const int seg0 = (blockIdx.x >> 1) * 16;
  const int tid  = threadIdx.x;
  const int wave = tid >> 6;
  const int lane = tid & 63;
  const int quad = lane >> 4;
  const int lc   = lane & 15;
  const int l8   = lane << 3;

  if (tid < 16){ ls[tid] = starts[seg0 + tid]; ll[tid] = a_scope[seg0 + tid]; }
  for (int i = tid; i < 4 * HPAD; i += 256) ((float*)lbias)[i] = gbias[dir * (4 * HPAD) + i];
  for (int i = tid; i < 16 * HPAD; i += 256){
    int m = i / HPAD, k = i - m * HPAD;
    float v = h0[(size_t)(seg0 + m) * HPAD + k];
    hfp[m][k] = v;
    hbuf[m][k] = f2bf(v);
  }
  __syncthreads();

  const short* PA = PkA + (size_t)dir * 409600;
  const short* PB = PkB + (size_t)dir * 204800;
  const int xm = tid >> 4, xu = tid & 15;

  for (int step = 0; step < MAXLEN; ++step){
    const int t = dir ? (MAXLEN - 1 - step) : step;
    {
      const bool valid = t < ll[xm];
      const float* src = node + (size_t)(ls[xm] + t) * HID;
      for (int k = xu; k < HPAD; k += 16){
        float v = 0.f;
        if (valid && k < HID){
          v = src[k] + bias[k];
          v = v > 0.f ? v : 0.f;
        }
        xbuf[xm][k] = f2bf(v);
      }
    }
    __syncthreads();

    f4v aR[5], aZ[5], aX[5], aH[5];
    #pragma unroll
    for (int i = 0; i < 5; ++i){
      aR[i] = f4v{0.f,0.f,0.f,0.f}; aZ[i] = f4v{0.f,0.f,0.f,0.f};
      aX[i] = f4v{0.f,0.f,0.f,0.f}; aH[i] = f4v{0.f,0.f,0.f,0.f};
    }
    #pragma unroll 2
    for (int kt = 0; kt < 10; ++kt){
      const int k0 = kt * 32 + quad * 8;
      const s8v a = *(const s8v*)&xbuf[lc][k0];
      #pragma unroll
      for (int i = 0; i < 5; ++i){
        const int jt = wave * 5 + i;
        const s8v bR = *(const s8v*)(PA + (size_t)((jt)      * 20 + kt) * 512 + l8);
        aR[i] = __builtin_amdgcn_mfma_f32_16x16x32_bf16(a, bR, aR[i], 0, 0, 0);
        const s8v bZ = *(const s8v*)(PA + (size_t)((20 + jt) * 20 + kt) * 512 + l8);
        aZ[i] = __builtin_amdgcn_mfma_f32_16x16x32_bf16(a, bZ, aZ[i], 0, 0, 0);
        const s8v bX = *(const s8v*)(PB + (size_t)((jt)      * 10 + kt) * 512 + l8);
        aX[i] = __builtin_amdgcn_mfma_f32_16x16x32_bf16(a, bX, aX[i], 0, 0, 0);
      }
    }
    #pragma unroll 2
    for (int kt = 0; kt < 10; ++kt){
      const int k0 = kt * 32 + quad * 8;
      const s8v a = *(const s8v*)&hbuf[lc][k0];
      #pragma unroll
      for (int i = 0; i < 5; ++i){
        const int jt = wave * 5 + i;
        const s8v bR = *(const s8v*)(PA + (size_t)((jt)      * 20 + 10 + kt) * 512 + l8);
        aR[i] = __builtin_amdgcn_mfma_f32_16x16x32_bf16(a, bR, aR[i], 0, 0, 0);
        const s8v bZ = *(const s8v*)(PA + (size_t)((20 + jt) * 20 + 10 + kt) * 512 + l8);
        aZ[i] = __builtin_amdgcn_mfma_f32_16x16x32_bf16(a, bZ, aZ[i], 0, 0, 0);
        const s8v bH = *(const s8v*)(PB + (size_t)((20 + jt) * 10 + kt) * 512 + l8);
        aH[i] = __builtin_amdgcn_mfma_f32_16x16x32_bf16(a, bH, aH[i], 0, 0, 0);
      }
    }
    __syncthreads();

    #pragma unroll
    for (int i = 0; i < 5; ++i){
      const int j = wave * 80 + i * 16 + lc;
      if (j < HID){
        const float bR = lbias[0][j], bZ = lbias[1][j];
        const float bX = lbias[2][j], bH = lbias[3][j];
        #pragma unroll
        for (int r = 0; r < 4; ++r){
          const int m = quad * 4 + r;
          const float rg = sigm(aR[i][r] + bR);
          const float zg = sigm(aZ[i][r] + bZ);
          const float ng = tanha(aX[i][r] + bX + rg * (aH[i][r] + bH));
          const float hold = hfp[m][j];
          const float hnew = (1.f - zg) * ng + zg * hold;
          hfp[m][j] = hnew;
          hbuf[m][j] = f2bf(hnew);
          if (t < ll[m])
            out[(size_t)(ls[m] + t) * 600 + dir * HID + j] = hnew;
        }
      }
    }
  }
}

// ---------------------------------------------------------------------------
extern "C" void kernel_launch(void* const* d_in, const int* in_sizes, int n_in,
                              void* d_out, int out_size, void* d_ws, size_t ws_size,
                              hipStream_t stream){
  const float* node    = (const float*)d_in[0];
  const int*   a_scope = (const int*)  d_in[1];
  // d_in[2] = max_len (always 128, hardcoded)
  const float* bias    = (const float*)d_in[3];
  const float* wih_f   = (const float*)d_in[4];
  const float* whh_f   = (const float*)d_in[5];
  const float* bih_f   = (const float*)d_in[6];
  const float* bhh_f   = (const float*)d_in[7];
  const float* wih_b   = (const float*)d_in[8];
  const float* whh_b   = (const float*)d_in[9];
  const float* bih_b   = (const float*)d_in[10];
  const float* bhh_b   = (const float*)d_in[11];
  float* out = (float*)d_out;

  char* ws = (char*)d_ws;
  int*   starts = (int*)  (ws + 0);          //     8,192 B
  float* h0     = (float*)(ws + 8192);       // 2,621,440 B -> 2,629,632

  scan_starts_k<<<1, 1024, 0, stream>>>(a_scope, starts);
  h0_max_k<<<NSEG, HPAD, 0, stream>>>(node, a_scope, starts, h0);

  const size_t FAST_NEED = 476956672ull;     // ~477 MB (xp bf16 both dirs)
  if (ws_size >= FAST_NEED){
    short* PkH = (short*)(ws + 2629632);     // 1,228,800 B
    short* PkI = (short*)(ws + 3858432);     // 1,228,800 B
    float* gb  = (float*)(ws + 5087232);     //    10,240 B
    short* xpb = (short*)(ws + 5097472);     // 471,859,200 B
    // perm/gmax alias the PkI region: PkI is dead once xp_gemm_k completes,
    // and sort_segs_k is launched after it (same stream, ordered).
    int* perm = (int*)(ws + 3858432);        //     8,192 B
    int* gmx  = (int*)(ws + 3858432 + 8192); //       512 B
    prep2_k<<<4810, 256, 0, stream>>>(wih_f, whh_f, bih_f, bhh_f,
                                      wih_b, whh_b, bih_b, bhh_b, PkH, PkI, gb);
    xp_gemm_k<<<2048, 256, 0, stream>>>(node, bias, PkI, xpb);
    sort_segs_k<<<1, 256, 0, stream>>>(a_scope, perm, gmx);
    gru4_k<<<256, 640, 0, stream>>>(a_scope, starts, perm, gmx, h0, PkH, gb, xpb, out);
  } else {
    short* PkA   = (short*)(ws + 2629632);   // 1,638,400 B
    short* PkB   = (short*)(ws + 4268032);   //   819,200 B
    float* gbias = (float*)(ws + 5087232);   //    10,240 B
    prep_k<<<4810, 256, 0, stream>>>(wih_f, whh_f, bih_f, bhh_f,
                                     wih_b, whh_b, bih_b, bhh_b, PkA, PkB, gbias);
    gru_k<<<256, 256, 0, stream>>>(node, bias, a_scope, starts, h0, PkA, PkB, gbias, out);
  }
}

// Round 2
// 2195.866 us; speedup vs baseline: 1.4318x; 1.4318x over previous
//
#include <hip/hip_runtime.h>
#include <cstddef>
#include <cstdint>

// ---------------------------------------------------------------------------
// BatchGRU round 6: weight residency WITHOUT the round-5 spill disaster.
// Round-5 post-mortem: Bp[2][3][3] (72 VGPR) + launch_bounds(640,3) made the
// allocator demote the "persistent" fragments to scratch (VGPR_Count=84!);
// scratch re-reads thrashed through the xp-flushed L3 to HBM (FETCH 235MB ->
// 2.6GB, MfmaUtil 10.3->4.2%). Round 6 (gru5_k):
//   - LDS weights kt 0..1 (114 KB, zero VGPR cost)
//   - VGPR-persistent kt 2..3 only (48 VGPR), guards removed (jt19 = zeros)
//   - streamed kt 4..9 (~360 KB/block-step, was 570 in gru3)
//   - xp rows cooperatively staged into LDS (xbuf, coalesced 8B loads;
//     zeros staged for invalid rows) -> kills 240 scattered 2B loads/step.
//     xg read from xbuf AFTER MFMA, BEFORE sync B (xbuf stable window).
//   - keep sort + forward early-exit (correct in round 5).
// LDS: 116,736 + 10,496 + 29,056 + 128 = 156.4 KB (1 block/CU, as before).
// ---------------------------------------------------------------------------

typedef short s8v __attribute__((ext_vector_type(8)));   // 8 x bf16 (bits)
typedef float f4v __attribute__((ext_vector_type(4)));   // MFMA accum

#define NSEG   2048
#define HID    300
#define HPAD   320
#define MAXLEN 128
#define NTOT   131072
#define PKSTRIDE 307200   // shorts per dir in PkH / PkI

__device__ __forceinline__ short f2bf(float f){
  unsigned u = __float_as_uint(f);
  u = (u + 0x7FFFu + ((u >> 16) & 1u)) >> 16;   // RNE
  return (short)u;
}
__device__ __forceinline__ float bf2f(unsigned short u){
  return __uint_as_float((unsigned)u << 16);
}
__device__ __forceinline__ float sigm(float x){ return 1.f / (1.f + __expf(-x)); }
__device__ __forceinline__ float tanha(float x){ return 1.f - 2.f / (__expf(2.f * x) + 1.f); }

// ---------------------------------------------------------------------------
// starts[b] = exclusive prefix sum of a_scope
// ---------------------------------------------------------------------------
__global__ __launch_bounds__(1024)
void scan_starts_k(const int* __restrict__ a_scope, int* __restrict__ starts){
  __shared__ int buf[2][NSEG];
  const int tid = threadIdx.x;
  for (int i = tid; i < NSEG; i += 1024) buf[0][i] = a_scope[i];
  __syncthreads();
  int src = 0;
  for (int off = 1; off < NSEG; off <<= 1){
    for (int i = tid; i < NSEG; i += 1024){
      int v = buf[src][i];
      if (i >= off) v += buf[src][i - off];
      buf[1 - src][i] = v;
    }
    __syncthreads();
    src ^= 1;
  }
  for (int i = tid; i < NSEG; i += 1024) starts[i] = buf[src][i] - a_scope[i];
}

// ---------------------------------------------------------------------------
// h0[b][k] = max over t<len of raw node[starts[b]+t][k]  (k>=HID -> 0 pad)
// ---------------------------------------------------------------------------
__global__ void h0_max_k(const float* __restrict__ node, const int* __restrict__ a_scope,
                         const int* __restrict__ starts, float* __restrict__ h0){
  const int b = blockIdx.x;
  const int k = threadIdx.x;              // 320 threads
  const int s = starts[b], len = a_scope[b];
  float m = 0.f;
  if (k < HID){
    m = -3.402823466e38f;
    const float* p = node + (size_t)s * HID + k;
    for (int t = 0; t < len; ++t) m = fmaxf(m, p[(size_t)t * HID]);
  }
  h0[(size_t)b * HPAD + k] = m;
}

// ---------------------------------------------------------------------------
// Counting sort of segments by length, DESCENDING (bin = 128 - len).
// ---------------------------------------------------------------------------
__global__ __launch_bounds__(256)
void sort_segs_k(const int* __restrict__ a_scope, int* __restrict__ perm,
                 int* __restrict__ gmax){
  __shared__ int cnt[MAXLEN + 1];
  __shared__ int sp[NSEG];
  const int tid = threadIdx.x;
  for (int i = tid; i < MAXLEN + 1; i += 256) cnt[i] = 0;
  __syncthreads();
  for (int i = tid; i < NSEG; i += 256) atomicAdd(&cnt[MAXLEN - a_scope[i]], 1);
  __syncthreads();
  if (tid == 0){
    int s = 0;
    for (int b = 0; b <= MAXLEN; ++b){ int c = cnt[b]; cnt[b] = s; s += c; }
  }
  __syncthreads();
  for (int i = tid; i < NSEG; i += 256){
    int p = atomicAdd(&cnt[MAXLEN - a_scope[i]], 1);
    sp[p] = i;
  }
  __syncthreads();
  for (int i = tid; i < NSEG; i += 256) perm[i] = sp[i];
  for (int g = tid; g < NSEG / 16; g += 256) gmax[g] = a_scope[sp[g * 16]];
}

// ===========================================================================
// FAST PATH
// ===========================================================================
// prep2: pack W_hh (PkH) and W_ih (PkI) into MFMA B-fragment order, bf16.
// Layout: [dir][sec 0..2 (r,z,n)][jt 0..19][kt 0..9][lane 0..63][e 0..7]
// gbias: [dir][4][320]  (r: bih+bhh, z: bih+bhh, xn: bih, hn: bhh)
// ---------------------------------------------------------------------------
__global__ void prep2_k(const float* __restrict__ wih_f, const float* __restrict__ whh_f,
                        const float* __restrict__ bih_f, const float* __restrict__ bhh_f,
                        const float* __restrict__ wih_b, const float* __restrict__ whh_b,
                        const float* __restrict__ bih_b, const float* __restrict__ bhh_b,
                        short* __restrict__ PkH, short* __restrict__ PkI,
                        float* __restrict__ gbias){
  const int idx = blockIdx.x * 256 + threadIdx.x;
  if (idx < 1228800){
    const bool isH = idx < 614400;
    int t = isH ? idx : idx - 614400;
    int e = t & 7, lane = (t >> 3) & 63;
    int r = t >> 9;
    int kt = r % 10; r /= 10;
    int jt = r % 20; r /= 20;
    int sec = r % 3, d = r / 3;          // per-dir stride = PKSTRIDE shorts
    const float* w = isH ? (d ? whh_b : whh_f) : (d ? wih_b : wih_f);
    int j = jt * 16 + (lane & 15);
    int k = kt * 32 + (lane >> 4) * 8 + e;
    float v = 0.f;
    if (j < HID && k < HID) v = w[(sec * HID + j) * HID + k];
    (isH ? PkH : PkI)[t] = f2bf(v);
  } else if (idx < 1228800 + 2560){
    int r3 = idx - 1228800;
    int d = r3 / 1280;
    int rem = r3 - d * 1280;
    int sec = rem / HPAD;
    int j = rem - sec * HPAD;
    const float* bih = d ? bih_b : bih_f;
    const float* bhh = d ? bhh_b : bhh_f;
    float v = 0.f;
    if (j < HID){
      if (sec == 0)      v = bih[j] + bhh[j];
      else if (sec == 1) v = bih[HID + j] + bhh[HID + j];
      else if (sec == 2) v = bih[2 * HID + j];
      else               v = bhh[2 * HID + j];
    }
    gbias[r3] = v;
  }
}

// ---------------------------------------------------------------------------
// xp GEMM: xp[dir][row][g] = (relu(node[row]+bias) @ W_ih_dir^T)[g], bf16.
// ---------------------------------------------------------------------------
__global__ __launch_bounds__(256)
void xp_gemm_k(const float* __restrict__ node, const float* __restrict__ bias,
               const short* __restrict__ PkI, short* __restrict__ xp){
  __shared__ __align__(16) short Bt[4 * 5120];   // 40 KB: 4 tiles x [10 kt][512]
  const int dir = blockIdx.x & 1;
  const int blk = blockIdx.x >> 1;               // 0..1023
  const int tid = threadIdx.x;
  const int wave = tid >> 6, lane = tid & 63;
  const int quad = lane >> 4, lc = lane & 15, l8 = lane << 3;
  const int rowbase = blk * 128 + wave * 32;
  const short* PI = PkI + (size_t)dir * PKSTRIDE;
  short* xpd = xp + (size_t)dir * ((size_t)NTOT * 900);

  s8v A[2][10];
  #pragma unroll
  for (int tm = 0; tm < 2; ++tm){
    const float* src = node + (size_t)(rowbase + tm * 16 + lc) * HID;
    #pragma unroll
    for (int kt = 0; kt < 10; ++kt){
      const int k0 = kt * 32 + quad * 8;
      s8v a;
      #pragma unroll
      for (int e = 0; e < 8; ++e){
        const int k = k0 + e;
        float v = 0.f;
        if (k < HID){ v = src[k] + bias[k]; v = v > 0.f ? v : 0.f; }
        a[e] = f2bf(v);
      }
      A[tm][kt] = a;
    }
  }

  for (int st0 = 0; st0 < 60; st0 += 4){
    __syncthreads();
    for (int i = tid; i < 2560; i += 256)
      ((s8v*)Bt)[i] = ((const s8v*)(PI + (size_t)st0 * 5120))[i];
    __syncthreads();
    #pragma unroll
    for (int u = 0; u < 4; ++u){
      const int st = st0 + u;                 // st = sec*20 + jt
      const int sec = st / 20, jt = st % 20;
      f4v a0 = {0.f,0.f,0.f,0.f}, a1 = {0.f,0.f,0.f,0.f};
      #pragma unroll
      for (int kt = 0; kt < 10; ++kt){
        const s8v b = *(const s8v*)&Bt[u * 5120 + kt * 512 + l8];
        a0 = __builtin_amdgcn_mfma_f32_16x16x32_bf16(A[0][kt], b, a0, 0, 0, 0);
        a1 = __builtin_amdgcn_mfma_f32_16x16x32_bf16(A[1][kt], b, a1, 0, 0, 0);
      }
      const int j = jt * 16 + lc;
      if (j < HID){
        const int g = sec * HID + j;
        #pragma unroll
        for (int r = 0; r < 4; ++r){
          const int rr = rowbase + quad * 4 + r;
          xpd[(size_t)rr * 900 + g]        = f2bf(a0[r]);
          xpd[(size_t)(rr + 16) * 900 + g] = f2bf(a1[r]);
        }
      }
    }
  }
}

// ---------------------------------------------------------------------------
// Recurrent kernel round 6 (gru5_k): 256 blocks (128 sorted seg-groups x 2
// dirs), 640 threads / 10 waves. Wave w owns jt {2w, 2w+1} (wave 9: jt 18
// real + jt 19 zero-pad, unguarded on the register path).
// Weights: kt 0..1 in LDS (114 tiles), kt 2..3 persistent VGPR (12 frags,
// 48 regs, NO conditional liveness), kt 4..9 streamed from L2.
// xp rows staged cooperatively into xbuf (zeros for invalid rows); xg read
// from xbuf after MFMA / before sync B (stable window, no extra barrier).
// ---------------------------------------------------------------------------
__global__ __launch_bounds__(640)
void gru5_k(const int* __restrict__ a_scope, const int* __restrict__ starts,
            const int* __restrict__ perm, const int* __restrict__ gmax,
            const float* __restrict__ h0, const short* __restrict__ PkH,
            const float* __restrict__ gbias, const short* __restrict__ xp,
            float* __restrict__ out){
  __shared__ __align__(16) short WL[114 * 512];   // 116,736 B: kt 0..1 weights
  __shared__ __align__(16) short hbuf[16][328];   //  10,496 B: bf16 h (A op)
  __shared__ __align__(16) short xbuf[16][908];   //  29,056 B: staged xp rows
  __shared__ int lsL[16], llL[16];

  const int dir  = blockIdx.x & 1;
  const int g    = blockIdx.x >> 1;
  const int seg0 = g * 16;
  const int tid  = threadIdx.x;
  const int wave = tid >> 6;
  const int lane = tid & 63;
  const int quad = lane >> 4;
  const int lc   = lane & 15;
  const int l8   = lane << 3;
  const int jt0  = 2 * wave;
  const int njt  = (jt0 < 18) ? 2 : 1;   // guards LDS weight path only

  const short* PH = PkH + (size_t)dir * PKSTRIDE;

  // ---- persistent B fragments kt 2..3 (48 VGPR, unguarded: jt19 = zeros) --
  s8v Bp[2][3][2];
  #pragma unroll
  for (int i = 0; i < 2; ++i)
    #pragma unroll
    for (int s = 0; s < 3; ++s)
      #pragma unroll
      for (int ktp = 0; ktp < 2; ++ktp)
        Bp[i][s][ktp] = *(const s8v*)(PH + (size_t)((s * 20 + jt0 + i) * 10 + 2 + ktp) * 512 + l8);

  // ---- LDS B fragments kt 0..1; tile id = wave*12 + (i*3+s)*2 + ktl ----
  #pragma unroll
  for (int i = 0; i < 2; ++i){
    if (i < njt){
      #pragma unroll
      for (int s = 0; s < 3; ++s)
        #pragma unroll
        for (int ktl = 0; ktl < 2; ++ktl)
          *(s8v*)&WL[(size_t)(wave * 12 + (i * 3 + s) * 2 + ktl) * 512 + l8] =
            *(const s8v*)(PH + (size_t)((s * 20 + jt0 + i) * 10 + ktl) * 512 + l8);
    }
  }

  // ---- segment meta into LDS ----
  if (tid < 16){
    const int sg = perm[seg0 + tid];
    lsL[tid] = starts[sg];
    llL[tid] = a_scope[sg];
  }

  // ---- init hbuf (16 x 320 over 640 threads) ----
  for (int i = tid; i < 16 * HPAD; i += 640){
    const int m = i / HPAD, k = i - m * HPAD;
    hbuf[m][k] = f2bf(h0[(size_t)perm[seg0 + m] * HPAD + k]);
  }

  // ---- per-thread h master + biases ----
  float hprev[2][4];
  float bR[2], bZ[2], bX[2], bH[2];
  bool  jv[2];
  #pragma unroll
  for (int i = 0; i < 2; ++i){
    const int jt = jt0 + i;
    const int j  = jt * 16 + lc;
    jv[i] = (jt < 19) && (j < HID);
    bR[i] = bZ[i] = bX[i] = bH[i] = 0.f;
    hprev[i][0] = hprev[i][1] = hprev[i][2] = hprev[i][3] = 0.f;
    if (jv[i]){
      bR[i] = gbias[dir * 1280 + 0 * HPAD + j];
      bZ[i] = gbias[dir * 1280 + 1 * HPAD + j];
      bX[i] = gbias[dir * 1280 + 2 * HPAD + j];
      bH[i] = gbias[dir * 1280 + 3 * HPAD + j];
      #pragma unroll
      for (int r = 0; r < 4; ++r)
        hprev[i][r] = h0[(size_t)perm[seg0 + quad * 4 + r] * HPAD + j];
    }
  }
  __syncthreads();

  // per-thread segment rows (m = quad*4 + r) and staging assignment
  int ls_r[4], ll_r[4];
  #pragma unroll
  for (int r = 0; r < 4; ++r){
    ls_r[r] = lsL[quad * 4 + r];
    ll_r[r] = llL[quad * 4 + r];
  }
  const int sm_ = tid / 40;            // staging row 0..15 (40 threads/row)
  const int su_ = tid - sm_ * 40;      // 8B chunk lane within row
  const int myls = lsL[sm_], myll = llL[sm_];

  const unsigned short* xpd = (const unsigned short*)xp + (size_t)dir * ((size_t)NTOT * 900);
  const int nsteps = dir ? MAXLEN : gmax[g];   // fwd: early-exit at group max

  for (int step = 0; step < nsteps; ++step){
    const int t = dir ? (MAXLEN - 1 - step) : step;

    // ---- stage xbuf(t): 16 rows x 900 shorts, coalesced 8B chunks ----
    {
      const bool sv = t < myll;
      const unsigned short* sp_ = xpd + (size_t)(myls + t) * 900;
      for (int u = su_; u < 225; u += 40){
        unsigned long long v = 0ull;
        if (sv) v = *(const unsigned long long*)(sp_ + u * 4);
        *(unsigned long long*)&xbuf[sm_][u * 4] = v;
      }
    }

    __syncthreads();   // hbuf(t) AND xbuf(t) complete

    // ---- h-GEMM: acc[i][sec], K=320 over kt 0..9 (LDS -> regs -> stream) --
    f4v acc[2][3];
    #pragma unroll
    for (int i = 0; i < 2; ++i)
      #pragma unroll
      for (int s = 0; s < 3; ++s)
        acc[i][s] = f4v{0.f, 0.f, 0.f, 0.f};

    // kt 0..1: LDS-resident
    #pragma unroll
    for (int ktl = 0; ktl < 2; ++ktl){
      const s8v a = *(const s8v*)&hbuf[lc][ktl * 32 + quad * 8];
      #pragma unroll
      for (int i = 0; i < 2; ++i){
        if (i < njt){
          #pragma unroll
          for (int s = 0; s < 3; ++s){
            const s8v b = *(const s8v*)&WL[(size_t)(wave * 12 + (i * 3 + s) * 2 + ktl) * 512 + l8];
            acc[i][s] = __builtin_amdgcn_mfma_f32_16x16x32_bf16(a, b, acc[i][s], 0, 0, 0);
          }
        }
      }
    }
    // kt 2..3: persistent VGPR fragments (unguarded)
    #pragma unroll
    for (int ktp = 0; ktp < 2; ++ktp){
      const s8v a = *(const s8v*)&hbuf[lc][(2 + ktp) * 32 + quad * 8];
      #pragma unroll
      for (int i = 0; i < 2; ++i)
        #pragma unroll
        for (int s = 0; s < 3; ++s)
          acc[i][s] = __builtin_amdgcn_mfma_f32_16x16x32_bf16(a, Bp[i][s][ktp], acc[i][s], 0, 0, 0);
    }
    // kt 4..9: streamed from L2 (unguarded; jt19 streams shared zero tiles)
    #pragma unroll 2
    for (int kt = 4; kt < 10; ++kt){
      const s8v a = *(const s8v*)&hbuf[lc][kt * 32 + quad * 8];
      #pragma unroll
      for (int i = 0; i < 2; ++i)
        #pragma unroll
        for (int s = 0; s < 3; ++s){
          const s8v b = *(const s8v*)(PH + (size_t)((s * 20 + jt0 + i) * 10 + kt) * 512 + l8);
          acc[i][s] = __builtin_amdgcn_mfma_f32_16x16x32_bf16(a, b, acc[i][s], 0, 0, 0);
        }
    }

    // ---- xg from xbuf (stable until sync B; zeros pre-staged for pad) ----
    float xg[2][4][3];
    #pragma unroll
    for (int i = 0; i < 2; ++i){
      const int j = (jt0 + i) * 16 + lc;
      #pragma unroll
      for (int r = 0; r < 4; ++r){
        const int m = quad * 4 + r;
        float vr = 0.f, vz = 0.f, vn = 0.f;
        if (jv[i]){
          vr = bf2f((unsigned short)xbuf[m][j]);
          vz = bf2f((unsigned short)xbuf[m][j + 300]);
          vn = bf2f((unsigned short)xbuf[m][j + 600]);
        }
        xg[i][r][0] = vr; xg[i][r][1] = vz; xg[i][r][2] = vn;
      }
    }

    __syncthreads();   // all waves done reading hbuf/xbuf before rewrite

    // ---- gates + h update + output (owning thread, registers only) ----
    #pragma unroll
    for (int i = 0; i < 2; ++i){
      if (jv[i]){
        const int j = (jt0 + i) * 16 + lc;
        #pragma unroll
        for (int r = 0; r < 4; ++r){
          const int m = quad * 4 + r;
          const float rg = sigm(acc[i][0][r] + bR[i] + xg[i][r][0]);
          const float zg = sigm(acc[i][1][r] + bZ[i] + xg[i][r][1]);
          const float ng = tanha(xg[i][r][2] + bX[i] + rg * (acc[i][2][r] + bH[i]));
          const float hnew = (1.f - zg) * ng + zg * hprev[i][r];
          hprev[i][r] = hnew;
          hbuf[m][j] = f2bf(hnew);
          if (t < ll_r[r])
            out[(size_t)(ls_r[r] + t) * 600 + dir * HID + j] = hnew;
        }
      }
    }
  }
}

// ===========================================================================
// FALLBACK PATH (round-1, known-passing) — used when ws_size is too small.
// ===========================================================================
__global__ void prep_k(const float* __restrict__ wih_f, const float* __restrict__ whh_f,
                       const float* __restrict__ bih_f, const float* __restrict__ bhh_f,
                       const float* __restrict__ wih_b, const float* __restrict__ whh_b,
                       const float* __restrict__ bih_b, const float* __restrict__ bhh_b,
                       short* __restrict__ PkA, short* __restrict__ PkB,
                       float* __restrict__ gbias){
  const int idx = blockIdx.x * 256 + threadIdx.x;
  if (idx < 819200){
    int e = idx & 7, lane = (idx >> 3) & 63;
    int r = idx >> 9;
    int kt = r % 20; r /= 20;
    int jt = r % 20; r /= 20;
    int sec = r & 1, d = r >> 1;
    const float* wih = d ? wih_b : wih_f;
    const float* whh = d ? whh_b : whh_f;
    int j = jt * 16 + (lane & 15);
    int k = kt * 32 + (lane >> 4) * 8 + e;
    float v = 0.f;
    if (j < HID){
      int row = sec * HID + j;
      if (k < HID)                    v = wih[row * HID + k];
      else if (k >= 320 && k < 620)   v = whh[row * HID + (k - 320)];
    }
    PkA[idx] = f2bf(v);
  } else if (idx < 819200 + 409600){
    int t = idx - 819200;
    int e = t & 7, lane = (t >> 3) & 63;
    int r = t >> 9;
    int kt = r % 10; r /= 10;
    int jt = r % 20; r /= 20;
    int sec = r & 1, d = r >> 1;
    const float* w = sec ? (d ? whh_b : whh_f) : (d ? wih_b : wih_f);
    int j = jt * 16 + (lane & 15);
    int k = kt * 32 + (lane >> 4) * 8 + e;
    float v = 0.f;
    if (j < HID && k < HID) v = w[(600 + j) * HID + k];
    PkB[t] = f2bf(v);
  } else if (idx < 819200 + 409600 + 2560){
    int r3 = idx - 819200 - 409600;
    int d = r3 / 1280;
    int rem = r3 - d * 1280;
    int sec = rem / HPAD;
    int j = rem - sec * HPAD;
    const float* bih = d ? bih_b : bih_f;
    const float* bhh = d ? bhh_b : bhh_f;
    float v = 0.f;
    if (j < HID){
      if (sec == 0)      v = bih[j] + bhh[j];
      else if (sec == 1) v = bih[HID + j] + bhh[HID + j];
      else if (sec == 2) v = bih[2 * HID + j];
      else               v = bhh[2 * HID + j];
    }
    gbias[r3] = v;
  }
}

__global__ __launch_bounds__(256)
void gru_k(const float* __restrict__ node, const float* __restrict__ bias,
           const int* __restrict__ a_scope, const int* __restrict__ starts,
           const float* __restrict__ h0, const short* __restrict__ PkA,
           const short* __restrict__ PkB, const float* __restrict__ gbias,
           float* __restrict__ out){
  __shared__ __align__(16) short xbuf[16][328];
  __shared__ __align__(16) short hbuf[16][328];
  __shared__ float hfp[16][324];
  __shared__ float lbias[4][HPAD];
  __shared__ int ls[16], ll[16];

  const int dir  = blockIdx.x & 1;
  const int seg0 = (blockIdx.x >> 1) * 16;
  const int tid  = threadIdx.x;
  const int wave = tid >> 6;
  const int lane = tid & 63;
  const int quad = lane >> 4;
  const int lc   = lane & 15;
  const int l8   = lane << 3;

  if (tid < 16){ ls[tid] = starts[seg0 + tid]; ll[tid] = a_scope[seg0 + tid]; }
  for (int i = tid; i < 4 * HPAD; i += 256) ((float*)lbias)[i] = gbias[dir * (4 * HPAD) + i];
  for (int i = tid; i < 16 * HPAD; i += 256){
    int m = i / HPAD, k = i - m * HPAD;
    float v = h0[(size_t)(seg0 + m) * HPAD + k];
    hfp[m][k] = v;
    hbuf[m][k] = f2bf(v);
  }
  __syncthreads();

  const short* PA = PkA + (size_t)dir * 409600;
  const short* PB = PkB + (size_t)dir * 204800;
  const int xm = tid >> 4, xu = tid & 15;

  for (int step = 0; step < MAXLEN; ++step){
    const int t = dir ? (MAXLEN - 1 - step) : step;
    {
      const bool valid = t < ll[xm];
      const float* src = node + (size_t)(ls[xm] + t) * HID;
      for (int k = xu; k < HPAD; k += 16){
        float v = 0.f;
        if (valid && k < HID){
          v = src[k] + bias[k];
          v = v > 0.f ? v : 0.f;
        }
        xbuf[xm][k] = f2bf(v);
      }
    }
    __syncthreads();

    f4v aR[5], aZ[5], aX[5], aH[5];
    #pragma unroll
    for (int i = 0; i < 5; ++i){
      aR[i] = f4v{0.f,0.f,0.f,0.f}; aZ[i] = f4v{0.f,0.f,0.f,0.f};
      aX[i] = f4v{0.f,0.f,0.f,0.f}; aH[i] = f4v{0.f,0.f,0.f,0.f};
    }
    #pragma unroll 2
    for (int kt = 0; kt < 10; ++kt){
      const int k0 = kt * 32 + quad * 8;
      const s8v a = *(const s8v*)&xbuf[lc][k0];
      #pragma unroll
      for (int i = 0; i < 5; ++i){
        const int jt = wave * 5 + i;
        const s8v bR = *(const s8v*)(PA + (size_t)((jt)      * 20 + kt) * 512 + l8);
        aR[i] = __builtin_amdgcn_mfma_f32_16x16x32_bf16(a, bR, aR[i], 0, 0, 0);
        const s8v bZ = *(const s8v*)(PA + (size_t)((20 + jt) * 20 + kt) * 512 + l8);
        aZ[i] = __builtin_amdgcn_mfma_f32_16x16x32_bf16(a, bZ, aZ[i], 0, 0, 0);
        const s8v bX = *(const s8v*)(PB + (size_t)((jt)      * 10 + kt) * 512 + l8);
        aX[i] = __builtin_amdgcn_mfma_f32_16x16x32_bf16(a, bX, aX[i], 0, 0, 0);
      }
    }
    #pragma unroll 2
    for (int kt = 0; kt < 10; ++kt){
      const int k0 = kt * 32 + quad * 8;
      const s8v a = *(const s8v*)&hbuf[lc][k0];
      #pragma unroll
      for (int i = 0; i < 5; ++i){
        const int jt = wave * 5 + i;
        const s8v bR = *(const s8v*)(PA + (size_t)((jt)      * 20 + 10 + kt) * 512 + l8);
        aR[i] = __builtin_amdgcn_mfma_f32_16x16x32_bf16(a, bR, aR[i], 0, 0, 0);
        const s8v bZ = *(const s8v*)(PA + (size_t)((20 + jt) * 20 + 10 + kt) * 512 + l8);
        aZ[i] = __builtin_amdgcn_mfma_f32_16x16x32_bf16(a, bZ, aZ[i], 0, 0, 0);
        const s8v bH = *(const s8v*)(PB + (size_t)((20 + jt) * 10 + kt) * 512 + l8);
        aH[i] = __builtin_amdgcn_mfma_f32_16x16x32_bf16(a, bH, aH[i], 0, 0, 0);
      }
    }
    __syncthreads();

    #pragma unroll
    for (int i = 0; i < 5; ++i){
      const int j = wave * 80 + i * 16 + lc;
      if (j < HID){
        const float bR = lbias[0][j], bZ = lbias[1][j];
        const float bX = lbias[2][j], bH = lbias[3][j];
        #pragma unroll
        for (int r = 0; r < 4; ++r){
          const int m = quad * 4 + r;
          const float rg = sigm(aR[i][r] + bR);
          const float zg = sigm(aZ[i][r] + bZ);
          const float ng = tanha(aX[i][r] + bX + rg * (aH[i][r] + bH));
          const float hold = hfp[m][j];
          const float hnew = (1.f - zg) * ng + zg * hold;
          hfp[m][j] = hnew;
          hbuf[m][j] = f2bf(hnew);
          if (t < ll[m])
            out[(size_t)(ls[m] + t) * 600 + dir * HID + j] = hnew;
        }
      }
    }
  }
}

// ---------------------------------------------------------------------------
extern "C" void kernel_launch(void* const* d_in, const int* in_sizes, int n_in,
                              void* d_out, int out_size, void* d_ws, size_t ws_size,
                              hipStream_t stream){
  const float* node    = (const float*)d_in[0];
  const int*   a_scope = (const int*)  d_in[1];
  // d_in[2] = max_len (always 128, hardcoded)
  const float* bias    = (const float*)d_in[3];
  const float* wih_f   = (const float*)d_in[4];
  const float* whh_f   = (const float*)d_in[5];
  const float* bih_f   = (const float*)d_in[6];
  const float* bhh_f   = (const float*)d_in[7];
  const float* wih_b   = (const float*)d_in[8];
  const float* whh_b   = (const float*)d_in[9];
  const float* bih_b   = (const float*)d_in[10];
  const float* bhh_b   = (const float*)d_in[11];
  float* out = (float*)d_out;

  char* ws = (char*)d_ws;
  int*   starts = (int*)  (ws + 0);          //     8,192 B
  float* h0     = (float*)(ws + 8192);       // 2,621,440 B -> 2,629,632

  scan_starts_k<<<1, 1024, 0, stream>>>(a_scope, starts);
  h0_max_k<<<NSEG, HPAD, 0, stream>>>(node, a_scope, starts, h0);

  const size_t FAST_NEED = 476956672ull;     // ~477 MB (xp bf16 both dirs)
  if (ws_size >= FAST_NEED){
    short* PkH = (short*)(ws + 2629632);     // 1,228,800 B
    short* PkI = (short*)(ws + 3858432);     // 1,228,800 B
    float* gb  = (float*)(ws + 5087232);     //    10,240 B
    short* xpb = (short*)(ws + 5097472);     // 471,859,200 B
    // perm/gmax alias the PkI region: PkI is dead once xp_gemm_k completes,
    // and sort_segs_k is launched after it (same stream, ordered).
    int* perm = (int*)(ws + 3858432);        //     8,192 B
    int* gmx  = (int*)(ws + 3858432 + 8192); //       512 B
    prep2_k<<<4810, 256, 0, stream>>>(wih_f, whh_f, bih_f, bhh_f,
                                      wih_b, whh_b, bih_b, bhh_b, PkH, PkI, gb);
    xp_gemm_k<<<2048, 256, 0, stream>>>(node, bias, PkI, xpb);
    sort_segs_k<<<1, 256, 0, stream>>>(a_scope, perm, gmx);
    gru5_k<<<256, 640, 0, stream>>>(a_scope, starts, perm, gmx, h0, PkH, gb, xpb, out);
  } else {
    short* PkA   = (short*)(ws + 2629632);   // 1,638,400 B
    short* PkB   = (short*)(ws + 4268032);   //   819,200 B
    float* gbias = (float*)(ws + 5087232);   //    10,240 B
    prep_k<<<4810, 256, 0, stream>>>(wih_f, whh_f, bih_f, bhh_f,
                                     wih_b, whh_b, bih_b, bhh_b, PkA, PkB, gbias);
    gru_k<<<256, 256, 0, stream>>>(node, bias, a_scope, starts, h0, PkA, PkB, gbias, out);
  }
}

// Round 4
// 1868.410 us; speedup vs baseline: 1.6828x; 1.1753x over previous
//
#include <hip/hip_runtime.h>
#include <cstddef>
#include <cstdint>

// ---------------------------------------------------------------------------
// BatchGRU round 8 = round 7 resubmit with a hardened barrier.
// Round-7 bench died in infra before producing data. Audit found one real
// hazard: separate asm("s_waitcnt lgkmcnt(0)") + __builtin_amdgcn_s_barrier()
// is NOT a compiler memory fence pair -- next-step ds_reads of hbuf could be
// hoisted between waitcnt and barrier (cross-wave LDS race). Fixed by fusing
// both instructions into ONE asm volatile with memory clobber. VMEM (out
// stores, xg prefetch loads) still crosses the barrier in flight.
// Design under test (unchanged):
//   - double-buffered hbuf[2] -> ONE lgkm-only barrier per step
//   - xg prefetched one step ahead into registers
//   - WL kt0..1 LDS-resident (120 tiles, guard-free), kt2..9 streamed
//   - sort + forward early-exit
// LDS: 122,880 (WL) + 20,992 (hbuf x2) + 128 = 144 KB.
// ---------------------------------------------------------------------------

typedef short s8v __attribute__((ext_vector_type(8)));   // 8 x bf16 (bits)
typedef float f4v __attribute__((ext_vector_type(4)));   // MFMA accum

#define NSEG   2048
#define HID    300
#define HPAD   320
#define MAXLEN 128
#define NTOT   131072
#define PKSTRIDE 307200   // shorts per dir in PkH / PkI

__device__ __forceinline__ short f2bf(float f){
  unsigned u = __float_as_uint(f);
  u = (u + 0x7FFFu + ((u >> 16) & 1u)) >> 16;   // RNE
  return (short)u;
}
__device__ __forceinline__ float bf2f(unsigned short u){
  return __uint_as_float((unsigned)u << 16);
}
__device__ __forceinline__ float sigm(float x){ return 1.f / (1.f + __expf(-x)); }
__device__ __forceinline__ float tanha(float x){ return 1.f - 2.f / (__expf(2.f * x) + 1.f); }

// ---------------------------------------------------------------------------
// starts[b] = exclusive prefix sum of a_scope
// ---------------------------------------------------------------------------
__global__ __launch_bounds__(1024)
void scan_starts_k(const int* __restrict__ a_scope, int* __restrict__ starts){
  __shared__ int buf[2][NSEG];
  const int tid = threadIdx.x;
  for (int i = tid; i < NSEG; i += 1024) buf[0][i] = a_scope[i];
  __syncthreads();
  int src = 0;
  for (int off = 1; off < NSEG; off <<= 1){
    for (int i = tid; i < NSEG; i += 1024){
      int v = buf[src][i];
      if (i >= off) v += buf[src][i - off];
      buf[1 - src][i] = v;
    }
    __syncthreads();
    src ^= 1;
  }
  for (int i = tid; i < NSEG; i += 1024) starts[i] = buf[src][i] - a_scope[i];
}

// ---------------------------------------------------------------------------
// h0[b][k] = max over t<len of raw node[starts[b]+t][k]  (k>=HID -> 0 pad)
// ---------------------------------------------------------------------------
__global__ void h0_max_k(const float* __restrict__ node, const int* __restrict__ a_scope,
                         const int* __restrict__ starts, float* __restrict__ h0){
  const int b = blockIdx.x;
  const int k = threadIdx.x;              // 320 threads
  const int s = starts[b], len = a_scope[b];
  float m = 0.f;
  if (k < HID){
    m = -3.402823466e38f;
    const float* p = node + (size_t)s * HID + k;
    for (int t = 0; t < len; ++t) m = fmaxf(m, p[(size_t)t * HID]);
  }
  h0[(size_t)b * HPAD + k] = m;
}

// ---------------------------------------------------------------------------
// Counting sort of segments by length, DESCENDING (bin = 128 - len).
// ---------------------------------------------------------------------------
__global__ __launch_bounds__(256)
void sort_segs_k(const int* __restrict__ a_scope, int* __restrict__ perm,
                 int* __restrict__ gmax){
  __shared__ int cnt[MAXLEN + 1];
  __shared__ int sp[NSEG];
  const int tid = threadIdx.x;
  for (int i = tid; i < MAXLEN + 1; i += 256) cnt[i] = 0;
  __syncthreads();
  for (int i = tid; i < NSEG; i += 256) atomicAdd(&cnt[MAXLEN - a_scope[i]], 1);
  __syncthreads();
  if (tid == 0){
    int s = 0;
    for (int b = 0; b <= MAXLEN; ++b){ int c = cnt[b]; cnt[b] = s; s += c; }
  }
  __syncthreads();
  for (int i = tid; i < NSEG; i += 256){
    int p = atomicAdd(&cnt[MAXLEN - a_scope[i]], 1);
    sp[p] = i;
  }
  __syncthreads();
  for (int i = tid; i < NSEG; i += 256) perm[i] = sp[i];
  for (int g = tid; g < NSEG / 16; g += 256) gmax[g] = a_scope[sp[g * 16]];
}

// ===========================================================================
// FAST PATH
// ===========================================================================
// prep2: pack W_hh (PkH) and W_ih (PkI) into MFMA B-fragment order, bf16.
// Layout: [dir][sec 0..2 (r,z,n)][jt 0..19][kt 0..9][lane 0..63][e 0..7]
// gbias: [dir][4][320]  (r: bih+bhh, z: bih+bhh, xn: bih, hn: bhh)
// ---------------------------------------------------------------------------
__global__ void prep2_k(const float* __restrict__ wih_f, const float* __restrict__ whh_f,
                        const float* __restrict__ bih_f, const float* __restrict__ bhh_f,
                        const float* __restrict__ wih_b, const float* __restrict__ whh_b,
                        const float* __restrict__ bih_b, const float* __restrict__ bhh_b,
                        short* __restrict__ PkH, short* __restrict__ PkI,
                        float* __restrict__ gbias){
  const int idx = blockIdx.x * 256 + threadIdx.x;
  if (idx < 1228800){
    const bool isH = idx < 614400;
    int t = isH ? idx : idx - 614400;
    int e = t & 7, lane = (t >> 3) & 63;
    int r = t >> 9;
    int kt = r % 10; r /= 10;
    int jt = r % 20; r /= 20;
    int sec = r % 3, d = r / 3;          // per-dir stride = PKSTRIDE shorts
    const float* w = isH ? (d ? whh_b : whh_f) : (d ? wih_b : wih_f);
    int j = jt * 16 + (lane & 15);
    int k = kt * 32 + (lane >> 4) * 8 + e;
    float v = 0.f;
    if (j < HID && k < HID) v = w[(sec * HID + j) * HID + k];
    (isH ? PkH : PkI)[t] = f2bf(v);
  } else if (idx < 1228800 + 2560){
    int r3 = idx - 1228800;
    int d = r3 / 1280;
    int rem = r3 - d * 1280;
    int sec = rem / HPAD;
    int j = rem - sec * HPAD;
    const float* bih = d ? bih_b : bih_f;
    const float* bhh = d ? bhh_b : bhh_f;
    float v = 0.f;
    if (j < HID){
      if (sec == 0)      v = bih[j] + bhh[j];
      else if (sec == 1) v = bih[HID + j] + bhh[HID + j];
      else if (sec == 2) v = bih[2 * HID + j];
      else               v = bhh[2 * HID + j];
    }
    gbias[r3] = v;
  }
}

// ---------------------------------------------------------------------------
// xp GEMM: xp[dir][row][g] = (relu(node[row]+bias) @ W_ih_dir^T)[g], bf16.
// ---------------------------------------------------------------------------
__global__ __launch_bounds__(256)
void xp_gemm_k(const float* __restrict__ node, const float* __restrict__ bias,
               const short* __restrict__ PkI, short* __restrict__ xp){
  __shared__ __align__(16) short Bt[4 * 5120];   // 40 KB: 4 tiles x [10 kt][512]
  const int dir = blockIdx.x & 1;
  const int blk = blockIdx.x >> 1;               // 0..1023
  const int tid = threadIdx.x;
  const int wave = tid >> 6, lane = tid & 63;
  const int quad = lane >> 4, lc = lane & 15, l8 = lane << 3;
  const int rowbase = blk * 128 + wave * 32;
  const short* PI = PkI + (size_t)dir * PKSTRIDE;
  short* xpd = xp + (size_t)dir * ((size_t)NTOT * 900);

  s8v A[2][10];
  #pragma unroll
  for (int tm = 0; tm < 2; ++tm){
    const float* src = node + (size_t)(rowbase + tm * 16 + lc) * HID;
    #pragma unroll
    for (int kt = 0; kt < 10; ++kt){
      const int k0 = kt * 32 + quad * 8;
      s8v a;
      #pragma unroll
      for (int e = 0; e < 8; ++e){
        const int k = k0 + e;
        float v = 0.f;
        if (k < HID){ v = src[k] + bias[k]; v = v > 0.f ? v : 0.f; }
        a[e] = f2bf(v);
      }
      A[tm][kt] = a;
    }
  }

  for (int st0 = 0; st0 < 60; st0 += 4){
    __syncthreads();
    for (int i = tid; i < 2560; i += 256)
      ((s8v*)Bt)[i] = ((const s8v*)(PI + (size_t)st0 * 5120))[i];
    __syncthreads();
    #pragma unroll
    for (int u = 0; u < 4; ++u){
      const int st = st0 + u;                 // st = sec*20 + jt
      const int sec = st / 20, jt = st % 20;
      f4v a0 = {0.f,0.f,0.f,0.f}, a1 = {0.f,0.f,0.f,0.f};
      #pragma unroll
      for (int kt = 0; kt < 10; ++kt){
        const s8v b = *(const s8v*)&Bt[u * 5120 + kt * 512 + l8];
        a0 = __builtin_amdgcn_mfma_f32_16x16x32_bf16(A[0][kt], b, a0, 0, 0, 0);
        a1 = __builtin_amdgcn_mfma_f32_16x16x32_bf16(A[1][kt], b, a1, 0, 0, 0);
      }
      const int j = jt * 16 + lc;
      if (j < HID){
        const int g = sec * HID + j;
        #pragma unroll
        for (int r = 0; r < 4; ++r){
          const int rr = rowbase + quad * 4 + r;
          xpd[(size_t)rr * 900 + g]        = f2bf(a0[r]);
          xpd[(size_t)(rr + 16) * 900 + g] = f2bf(a1[r]);
        }
      }
    }
  }
}

// ---------------------------------------------------------------------------
// Recurrent kernel (gru6_k): 256 blocks (128 sorted seg-groups x 2 dirs),
// 640 threads / 10 waves, wave w owns jt {2w, 2w+1} (jt19 = zeros).
// Double-buffered hbuf -> ONE fused lgkmcnt(0)+s_barrier per step (single
// asm, memory clobber: compiler cannot move LDS ops across it; VMEM stays
// in flight). xg prefetched one step ahead into registers.
// Weights: kt0..1 LDS-resident (120 tiles), kt2..9 streamed from L2.
// ---------------------------------------------------------------------------
__global__ __launch_bounds__(640)
void gru6_k(const int* __restrict__ a_scope, const int* __restrict__ starts,
            const int* __restrict__ perm, const int* __restrict__ gmax,
            const float* __restrict__ h0, const short* __restrict__ PkH,
            const float* __restrict__ gbias, const short* __restrict__ xp,
            float* __restrict__ out){
  __shared__ __align__(16) short WL[120 * 512];    // 122,880 B: kt 0..1 weights
  __shared__ __align__(16) short hbuf[2][16][328]; //  20,992 B: double-buffered h
  __shared__ int lsL[16], llL[16];

  const int dir  = blockIdx.x & 1;
  const int g    = blockIdx.x >> 1;
  const int seg0 = g * 16;
  const int tid  = threadIdx.x;
  const int wave = tid >> 6;
  const int lane = tid & 63;
  const int quad = lane >> 4;
  const int lc   = lane & 15;
  const int l8   = lane << 3;
  const int jt0  = 2 * wave;

  const short* PH = PkH + (size_t)dir * PKSTRIDE;

  // ---- LDS B fragments kt 0..1 (all 20 jt incl. zero-pad jt19) ----
  #pragma unroll
  for (int i = 0; i < 2; ++i)
    #pragma unroll
    for (int s = 0; s < 3; ++s)
      #pragma unroll
      for (int ktl = 0; ktl < 2; ++ktl)
        *(s8v*)&WL[(size_t)(wave * 12 + (i * 3 + s) * 2 + ktl) * 512 + l8] =
          *(const s8v*)(PH + (size_t)((s * 20 + jt0 + i) * 10 + ktl) * 512 + l8);

  // ---- segment meta ----
  if (tid < 16){
    const int sg = perm[seg0 + tid];
    lsL[tid] = starts[sg];
    llL[tid] = a_scope[sg];
  }

  // ---- init hbuf[0] = h0 (bf16), hbuf[1] = 0 (pad cols stay 0 forever) ----
  for (int i = tid; i < 16 * HPAD; i += 640){
    const int m = i / HPAD, k = i - m * HPAD;
    hbuf[0][m][k] = f2bf(h0[(size_t)perm[seg0 + m] * HPAD + k]);
    hbuf[1][m][k] = 0;
  }

  // ---- per-thread h master + biases ----
  float hprev[2][4];
  float bR[2], bZ[2], bX[2], bH[2];
  bool  jv[2];
  #pragma unroll
  for (int i = 0; i < 2; ++i){
    const int jt = jt0 + i;
    const int j  = jt * 16 + lc;
    jv[i] = (jt < 19) && (j < HID);
    bR[i] = bZ[i] = bX[i] = bH[i] = 0.f;
    hprev[i][0] = hprev[i][1] = hprev[i][2] = hprev[i][3] = 0.f;
    if (jv[i]){
      bR[i] = gbias[dir * 1280 + 0 * HPAD + j];
      bZ[i] = gbias[dir * 1280 + 1 * HPAD + j];
      bX[i] = gbias[dir * 1280 + 2 * HPAD + j];
      bH[i] = gbias[dir * 1280 + 3 * HPAD + j];
      #pragma unroll
      for (int r = 0; r < 4; ++r)
        hprev[i][r] = h0[(size_t)perm[seg0 + quad * 4 + r] * HPAD + j];
    }
  }
  __syncthreads();   // full barrier once: WL, lsL, hbuf visible

  int ls_r[4], ll_r[4];
  #pragma unroll
  for (int r = 0; r < 4; ++r){
    ls_r[r] = lsL[quad * 4 + r];
    ll_r[r] = llL[quad * 4 + r];
  }

  const unsigned short* xpd = (const unsigned short*)xp + (size_t)dir * ((size_t)NTOT * 900);
  const int nsteps = dir ? MAXLEN : gmax[g];   // fwd: early-exit at group max

  // ---- xg prefetch registers (raw bf16 bits), one step ahead ----
  unsigned short xgr[2][4][3];
  {
    const int t0 = dir ? (MAXLEN - 1) : 0;
    #pragma unroll
    for (int r = 0; r < 4; ++r){
      int idx = ls_r[r] + t0; if (idx > NTOT - 1) idx = NTOT - 1;
      const unsigned short* p = xpd + (size_t)idx * 900;
      #pragma unroll
      for (int i = 0; i < 2; ++i){
        const unsigned short* pj = p + (jv[i] ? ((jt0 + i) * 16 + lc) : 0);
        xgr[i][r][0] = pj[0]; xgr[i][r][1] = pj[300]; xgr[i][r][2] = pj[600];
      }
    }
  }

  int cur = 0;
  for (int step = 0; step < nsteps; ++step){
    const int t = dir ? (MAXLEN - 1 - step) : step;

    // ---- h-GEMM: acc[i][sec], K=320 (kt0..1 LDS, kt2..9 streamed) ----
    f4v acc[2][3];
    #pragma unroll
    for (int i = 0; i < 2; ++i)
      #pragma unroll
      for (int s = 0; s < 3; ++s)
        acc[i][s] = f4v{0.f, 0.f, 0.f, 0.f};

    #pragma unroll
    for (int ktl = 0; ktl < 2; ++ktl){
      const s8v a = *(const s8v*)&hbuf[cur][lc][ktl * 32 + quad * 8];
      #pragma unroll
      for (int i = 0; i < 2; ++i)
        #pragma unroll
        for (int s = 0; s < 3; ++s){
          const s8v b = *(const s8v*)&WL[(size_t)(wave * 12 + (i * 3 + s) * 2 + ktl) * 512 + l8];
          acc[i][s] = __builtin_amdgcn_mfma_f32_16x16x32_bf16(a, b, acc[i][s], 0, 0, 0);
        }
    }
    #pragma unroll 4
    for (int kt = 2; kt < 10; ++kt){
      const s8v a = *(const s8v*)&hbuf[cur][lc][kt * 32 + quad * 8];
      #pragma unroll
      for (int i = 0; i < 2; ++i)
        #pragma unroll
        for (int s = 0; s < 3; ++s){
          const s8v b = *(const s8v*)(PH + (size_t)((s * 20 + jt0 + i) * 10 + kt) * 512 + l8);
          acc[i][s] = __builtin_amdgcn_mfma_f32_16x16x32_bf16(a, b, acc[i][s], 0, 0, 0);
        }
    }

    // ---- gates + h update + output (xg from prefetch regs) ----
    #pragma unroll
    for (int i = 0; i < 2; ++i){
      if (jv[i]){
        const int j = (jt0 + i) * 16 + lc;
        #pragma unroll
        for (int r = 0; r < 4; ++r){
          const int m = quad * 4 + r;
          const bool v = t < ll_r[r];
          const float xr = v ? bf2f(xgr[i][r][0]) : 0.f;
          const float xz = v ? bf2f(xgr[i][r][1]) : 0.f;
          const float xn = v ? bf2f(xgr[i][r][2]) : 0.f;
          const float rg = sigm(acc[i][0][r] + bR[i] + xr);
          const float zg = sigm(acc[i][1][r] + bZ[i] + xz);
          const float ng = tanha(xn + bX[i] + rg * (acc[i][2][r] + bH[i]));
          const float hnew = (1.f - zg) * ng + zg * hprev[i][r];
          hprev[i][r] = hnew;
          hbuf[cur ^ 1][m][j] = f2bf(hnew);
          if (v) out[(size_t)(ls_r[r] + t) * 600 + dir * HID + j] = hnew;
        }
      }
    }

    // ---- prefetch xg for next step (in flight across the barrier) ----
    {
      int tn = dir ? (t - 1) : (t + 1);
      if (tn < 0) tn = 0;
      if (tn > MAXLEN - 1) tn = MAXLEN - 1;
      #pragma unroll
      for (int r = 0; r < 4; ++r){
        int idx = ls_r[r] + tn; if (idx > NTOT - 1) idx = NTOT - 1;
        const unsigned short* p = xpd + (size_t)idx * 900;
        #pragma unroll
        for (int i = 0; i < 2; ++i){
          const unsigned short* pj = p + (jv[i] ? ((jt0 + i) * 16 + lc) : 0);
          xgr[i][r][0] = pj[0]; xgr[i][r][1] = pj[300]; xgr[i][r][2] = pj[600];
        }
      }
    }

    // ---- fused LDS-coherent barrier (single asm: nothing crosses it at
    //      compile time; VMEM stays in flight at runtime) ----
    asm volatile("s_waitcnt lgkmcnt(0)\n\ts_barrier" ::: "memory");
    cur ^= 1;
  }
}

// ===========================================================================
// FALLBACK PATH (round-1, known-passing) — used when ws_size is too small.
// ===========================================================================
__global__ void prep_k(const float* __restrict__ wih_f, const float* __restrict__ whh_f,
                       const float* __restrict__ bih_f, const float* __restrict__ bhh_f,
                       const float* __restrict__ wih_b, const float* __restrict__ whh_b,
                       const float* __restrict__ bih_b, const float* __restrict__ bhh_b,
                       short* __restrict__ PkA, short* __restrict__ PkB,
                       float* __restrict__ gbias){
  const int idx = blockIdx.x * 256 + threadIdx.x;
  if (idx < 819200){
    int e = idx & 7, lane = (idx >> 3) & 63;
    int r = idx >> 9;
    int kt = r % 20; r /= 20;
    int jt = r % 20; r /= 20;
    int sec = r & 1, d = r >> 1;
    const float* wih = d ? wih_b : wih_f;
    const float* whh = d ? whh_b : whh_f;
    int j = jt * 16 + (lane & 15);
    int k = kt * 32 + (lane >> 4) * 8 + e;
    float v = 0.f;
    if (j < HID){
      int row = sec * HID + j;
      if (k < HID)                    v = wih[row * HID + k];
      else if (k >= 320 && k < 620)   v = whh[row * HID + (k - 320)];
    }
    PkA[idx] = f2bf(v);
  } else if (idx < 819200 + 409600){
    int t = idx - 819200;
    int e = t & 7, lane = (t >> 3) & 63;
    int r = t >> 9;
    int kt = r % 10; r /= 10;
    int jt = r % 20; r /= 20;
    int sec = r & 1, d = r >> 1;
    const float* w = sec ? (d ? whh_b : whh_f) : (d ? wih_b : wih_f);
    int j = jt * 16 + (lane & 15);
    int k = kt * 32 + (lane >> 4) * 8 + e;
    float v = 0.f;
    if (j < HID && k < HID) v = w[(600 + j) * HID + k];
    PkB[t] = f2bf(v);
  } else if (idx < 819200 + 409600 + 2560){
    int r3 = idx - 819200 - 409600;
    int d = r3 / 1280;
    int rem = r3 - d * 1280;
    int sec = rem / HPAD;
    int j = rem - sec * HPAD;
    const float* bih = d ? bih_b : bih_f;
    const float* bhh = d ? bhh_b : bhh_f;
    float v = 0.f;
    if (j < HID){
      if (sec == 0)      v = bih[j] + bhh[j];
      else if (sec == 1) v = bih[HID + j] + bhh[HID + j];
      else if (sec == 2) v = bih[2 * HID + j];
      else               v = bhh[2 * HID + j];
    }
    gbias[r3] = v;
  }
}

__global__ __launch_bounds__(256)
void gru_k(const float* __restrict__ node, const float* __restrict__ bias,
           const int* __restrict__ a_scope, const int* __restrict__ starts,
           const float* __restrict__ h0, const short* __restrict__ PkA,
           const short* __restrict__ PkB, const float* __restrict__ gbias,
           float* __restrict__ out){
  __shared__ __align__(16) short xbuf[16][328];
  __shared__ __align__(16) short hbuf[16][328];
  __shared__ float hfp[16][324];
  __shared__ float lbias[4][HPAD];
  __shared__ int ls[16], ll[16];

  const int dir  = blockIdx.x & 1;
  const int seg0 = (blockIdx.x >> 1) * 16;
  const int tid  = threadIdx.x;
  const int wave = tid >> 6;
  const int lane = tid & 63;
  const int quad = lane >> 4;
  const int lc   = lane & 15;
  const int l8   = lane << 3;

  if (tid < 16){ ls[tid] = starts[seg0 + tid]; ll[tid] = a_scope[seg0 + tid]; }
  for (int i = tid; i < 4 * HPAD; i += 256) ((float*)lbias)[i] = gbias[dir * (4 * HPAD) + i];
  for (int i = tid; i < 16 * HPAD; i += 256){
    int m = i / HPAD, k = i - m * HPAD;
    float v = h0[(size_t)(seg0 + m) * HPAD + k];
    hfp[m][k] = v;
    hbuf[m][k] = f2bf(v);
  }
  __syncthreads();

  const short* PA = PkA + (size_t)dir * 409600;
  const short* PB = PkB + (size_t)dir * 204800;
  const int xm = tid >> 4, xu = tid & 15;

  for (int step = 0; step < MAXLEN; ++step){
    const int t = dir ? (MAXLEN - 1 - step) : step;
    {
      const bool valid = t < ll[xm];
      const float* src = node + (size_t)(ls[xm] + t) * HID;
      for (int k = xu; k < HPAD; k += 16){
        float v = 0.f;
        if (valid && k < HID){
          v = src[k] + bias[k];
          v = v > 0.f ? v : 0.f;
        }
        xbuf[xm][k] = f2bf(v);
      }
    }
    __syncthreads();

    f4v aR[5], aZ[5], aX[5], aH[5];
    #pragma unroll
    for (int i = 0; i < 5; ++i){
      aR[i] = f4v{0.f,0.f,0.f,0.f}; aZ[i] = f4v{0.f,0.f,0.f,0.f};
      aX[i] = f4v{0.f,0.f,0.f,0.f}; aH[i] = f4v{0.f,0.f,0.f,0.f};
    }
    #pragma unroll 2
    for (int kt = 0; kt < 10; ++kt){
      const int k0 = kt * 32 + quad * 8;
      const s8v a = *(const s8v*)&xbuf[lc][k0];
      #pragma unroll
      for (int i = 0; i < 5; ++i){
        const int jt = wave * 5 + i;
        const s8v bR = *(const s8v*)(PA + (size_t)((jt)      * 20 + kt) * 512 + l8);
        aR[i] = __builtin_amdgcn_mfma_f32_16x16x32_bf16(a, bR, aR[i], 0, 0, 0);
        const s8v bZ = *(const s8v*)(PA + (size_t)((20 + jt) * 20 + kt) * 512 + l8);
        aZ[i] = __builtin_amdgcn_mfma_f32_16x16x32_bf16(a, bZ, aZ[i], 0, 0, 0);
        const s8v bX = *(const s8v*)(PB + (size_t)((jt)      * 10 + kt) * 512 + l8);
        aX[i] = __builtin_amdgcn_mfma_f32_16x16x32_bf16(a, bX, aX[i], 0, 0, 0);
      }
    }
    #pragma unroll 2
    for (int kt = 0; kt < 10; ++kt){
      const int k0 = kt * 32 + quad * 8;
      const s8v a = *(const s8v*)&hbuf[lc][k0];
      #pragma unroll
      for (int i = 0; i < 5; ++i){
        const int jt = wave * 5 + i;
        const s8v bR = *(const s8v*)(PA + (size_t)((jt)      * 20 + 10 + kt) * 512 + l8);
        aR[i] = __builtin_amdgcn_mfma_f32_16x16x32_bf16(a, bR, aR[i], 0, 0, 0);
        const s8v bZ = *(const s8v*)(PA + (size_t)((20 + jt) * 20 + 10 + kt) * 512 + l8);
        aZ[i] = __builtin_amdgcn_mfma_f32_16x16x32_bf16(a, bZ, aZ[i], 0, 0, 0);
        const s8v bH = *(const s8v*)(PB + (size_t)((20 + jt) * 10 + kt) * 512 + l8);
        aH[i] = __builtin_amdgcn_mfma_f32_16x16x32_bf16(a, bH, aH[i], 0, 0, 0);
      }
    }
    __syncthreads();

    #pragma unroll
    for (int i = 0; i < 5; ++i){
      const int j = wave * 80 + i * 16 + lc;
      if (j < HID){
        const float bR = lbias[0][j], bZ = lbias[1][j];
        const float bX = lbias[2][j], bH = lbias[3][j];
        #pragma unroll
        for (int r = 0; r < 4; ++r){
          const int m = quad * 4 + r;
          const float rg = sigm(aR[i][r] + bR);
          const float zg = sigm(aZ[i][r] + bZ);
          const float ng = tanha(aX[i][r] + bX + rg * (aH[i][r] + bH));
          const float hold = hfp[m][j];
          const float hnew = (1.f - zg) * ng + zg * hold;
          hfp[m][j] = hnew;
          hbuf[m][j] = f2bf(hnew);
          if (t < ll[m])
            out[(size_t)(ls[m] + t) * 600 + dir * HID + j] = hnew;
        }
      }
    }
  }
}

// ---------------------------------------------------------------------------
extern "C" void kernel_launch(void* const* d_in, const int* in_sizes, int n_in,
                              void* d_out, int out_size, void* d_ws, size_t ws_size,
                              hipStream_t stream){
  const float* node    = (const float*)d_in[0];
  const int*   a_scope = (const int*)  d_in[1];
  // d_in[2] = max_len (always 128, hardcoded)
  const float* bias    = (const float*)d_in[3];
  const float* wih_f   = (const float*)d_in[4];
  const float* whh_f   = (const float*)d_in[5];
  const float* bih_f   = (const float*)d_in[6];
  const float* bhh_f   = (const float*)d_in[7];
  const float* wih_b   = (const float*)d_in[8];
  const float* whh_b   = (const float*)d_in[9];
  const float* bih_b   = (const float*)d_in[10];
  const float* bhh_b   = (const float*)d_in[11];
  float* out = (float*)d_out;

  char* ws = (char*)d_ws;
  int*   starts = (int*)  (ws + 0);          //     8,192 B
  float* h0     = (float*)(ws + 8192);       // 2,621,440 B -> 2,629,632

  scan_starts_k<<<1, 1024, 0, stream>>>(a_scope, starts);
  h0_max_k<<<NSEG, HPAD, 0, stream>>>(node, a_scope, starts, h0);

  const size_t FAST_NEED = 476956672ull;     // ~477 MB (xp bf16 both dirs)
  if (ws_size >= FAST_NEED){
    short* PkH = (short*)(ws + 2629632);     // 1,228,800 B
    short* PkI = (short*)(ws + 3858432);     // 1,228,800 B
    float* gb  = (float*)(ws + 5087232);     //    10,240 B
    short* xpb = (short*)(ws + 5097472);     // 471,859,200 B
    // perm/gmax alias the PkI region: PkI is dead once xp_gemm_k completes,
    // and sort_segs_k is launched after it (same stream, ordered).
    int* perm = (int*)(ws + 3858432);        //     8,192 B
    int* gmx  = (int*)(ws + 3858432 + 8192); //       512 B
    prep2_k<<<4810, 256, 0, stream>>>(wih_f, whh_f, bih_f, bhh_f,
                                      wih_b, whh_b, bih_b, bhh_b, PkH, PkI, gb);
    xp_gemm_k<<<2048, 256, 0, stream>>>(node, bias, PkI, xpb);
    sort_segs_k<<<1, 256, 0, stream>>>(a_scope, perm, gmx);
    gru6_k<<<256, 640, 0, stream>>>(a_scope, starts, perm, gmx, h0, PkH, gb, xpb, out);
  } else {
    short* PkA   = (short*)(ws + 2629632);   // 1,638,400 B
    short* PkB   = (short*)(ws + 4268032);   //   819,200 B
    float* gbias = (float*)(ws + 5087232);   //    10,240 B
    prep_k<<<4810, 256, 0, stream>>>(wih_f, whh_f, bih_f, bhh_f,
                                     wih_b, whh_b, bih_b, bhh_b, PkA, PkB, gbias);
    gru_k<<<256, 256, 0, stream>>>(node, bias, a_scope, starts, h0, PkA, PkB, gbias, out);
  }
}